// Round 1
// baseline (5351.017 us; speedup 1.0000x reference)
//
#include <hip/hip_runtime.h>

#define B_  4
#define ROI 90
#define T_  200
#define H_  3
#define F_  96
#define G3  288

typedef _Float16 f16x2 __attribute__((ext_vector_type(2)));

union F4H { float4 v; f16x2 h[4]; };

__device__ __forceinline__ float dot2acc(f16x2 a, f16x2 b, float c) {
#if __has_builtin(__builtin_amdgcn_fdot2)
    return __builtin_amdgcn_fdot2(a, b, c, false);
#else
    return c + (float)a.x * (float)b.x + (float)a.y * (float)b.y;
#endif
}

// ---------------------------------------------------------------------------
// Stage A: per-(b,t,h) block: sparse aggregation + 2-layer MLP (BN+ELU) + relu
// Writes h into d_out at the FINAL output layout index (b, roi, t, hb, f) so
// stage C can run the GRU in place (read-before-overwrite per t).
// ---------------------------------------------------------------------------
__global__ __launch_bounds__(384) void stageA(
    const float* __restrict__ x, const float* __restrict__ a,
    const float* __restrict__ eps,
    const float* __restrict__ W1, const float* __restrict__ b1,
    const float* __restrict__ g1, const float* __restrict__ be1,
    const float* __restrict__ W2, const float* __restrict__ b2,
    const float* __restrict__ g2, const float* __restrict__ be2,
    float* __restrict__ hbuf)
{
    __shared__ __align__(16) f16x2 xs[ROI][48];   // x tile f16; reused as h1
    __shared__ __align__(16) f16x2 agg[ROI][48];  // aggregated tile f16
    __shared__ __align__(16) f16x2 wbuf[96][49];  // W1 then W2 (transposed, k-paired, padded)
    __shared__ unsigned char jl[ROI][ROI];        // per-row nonzero col indices
    __shared__ int cnt[ROI];

    const int blk = blockIdx.x;
    const int bb  = blk / (T_ * H_);
    const int rem = blk % (T_ * H_);
    const int t   = rem / H_;
    const int hb  = rem % H_;
    const int tid = threadIdx.x;

    // ---- load x tile (90 x 96 fp32 -> f16 pairs) ----
    for (int idx = tid; idx < ROI * 24; idx += 384) {
        const int j = idx / 24, c4 = idx % 24;
        const float4 v = *(const float4*)(x + ((((long)bb * ROI + j) * T_ + t) * H_ + hb) * F_ + c4 * 4);
        f16x2 p0 = { (_Float16)v.x, (_Float16)v.y };
        f16x2 p1 = { (_Float16)v.z, (_Float16)v.w };
        xs[j][c4 * 2]     = p0;
        xs[j][c4 * 2 + 1] = p1;
    }
    // ---- load W1 transposed+paired: wbuf[f2][p] = (W1[2p][f2], W1[2p+1][f2]) ----
    for (int idx = tid; idx < 48 * 96; idx += 384) {
        const int f2 = idx % 96, fp = idx / 96;
        f16x2 p = { (_Float16)W1[(2 * fp) * 96 + f2], (_Float16)W1[(2 * fp + 1) * 96 + f2] };
        wbuf[f2][fp] = p;
    }
    if (tid < ROI) cnt[tid] = 0;
    const float epsv = eps[0];
    __syncthreads();

    // ---- compress adjacency (mask = a != 0 -> exact 1.0 weights -> adds) ----
    for (int idx = tid; idx < ROI * ROI; idx += 384) {
        const int i = idx / ROI, j = idx % ROI;
        const float av = a[((((long)bb * ROI + i) * T_ + t) * H_ + hb) * ROI + j];
        if (av != 0.0f) {
            const int p = atomicAdd(&cnt[i], 1);
            jl[i][p] = (unsigned char)j;
        }
    }
    __syncthreads();

    // ---- agg[i] = sum_{j in list(i)} xs[j] + eps * xs[i] ----
    for (int idx = tid; idx < ROI * 48; idx += 384) {
        const int i = idx / 48, p = idx % 48;
        float s0 = 0.f, s1 = 0.f;
        const int c = cnt[i];
        for (int q = 0; q < c; q++) {
            const f16x2 v = xs[jl[i][q]][p];
            s0 += (float)v.x; s1 += (float)v.y;
        }
        const f16x2 xi = xs[i][p];
        s0 += epsv * (float)xi.x;
        s1 += epsv * (float)xi.y;
        f16x2 o = { (_Float16)s0, (_Float16)s1 };
        agg[i][p] = o;
    }
    __syncthreads();

    const int f2 = tid % 96, isub = tid / 96;   // thread owns output column f2
    f16x2 w[48];
    #pragma unroll
    for (int p = 0; p < 48; p++) w[p] = wbuf[f2][p];   // W column -> registers
    {
        const float bia = b1[f2];
        const float sc  = g1[f2] * rsqrtf(1.0f + 1e-5f);
        const float sh  = be1[f2];
        _Float16* h1h = (_Float16*)xs;   // xs no longer needed; reuse for h1
        for (int i = isub; i < ROI; i += 4) {
            const F4H* ar = (const F4H*)&agg[i][0];
            float acc = 0.f;
            #pragma unroll
            for (int q = 0; q < 12; q++) {
                F4H u = ar[q];
                acc = dot2acc(u.h[0], w[4 * q],     acc);
                acc = dot2acc(u.h[1], w[4 * q + 1], acc);
                acc = dot2acc(u.h[2], w[4 * q + 2], acc);
                acc = dot2acc(u.h[3], w[4 * q + 3], acc);
            }
            float y = (acc + bia) * sc + sh;   // BN (eval mode)
            y = y > 0.f ? y : expm1f(y);       // ELU
            h1h[i * 96 + f2] = (_Float16)y;
        }
    }
    __syncthreads();
    // ---- reload W2 over the same buffer (keeps LDS <= 62 KB) ----
    for (int idx = tid; idx < 48 * 96; idx += 384) {
        const int f2b = idx % 96, fp = idx / 96;
        f16x2 p = { (_Float16)W2[(2 * fp) * 96 + f2b], (_Float16)W2[(2 * fp + 1) * 96 + f2b] };
        wbuf[f2b][fp] = p;
    }
    __syncthreads();
    #pragma unroll
    for (int p = 0; p < 48; p++) w[p] = wbuf[f2][p];
    {
        const float bia = b2[f2];
        const float sc  = g2[f2] * rsqrtf(1.0f + 1e-5f);
        const float sh  = be2[f2];
        for (int i = isub; i < ROI; i += 4) {
            const F4H* hr = (const F4H*)&xs[i][0];
            float acc = 0.f;
            #pragma unroll
            for (int q = 0; q < 12; q++) {
                F4H u = hr[q];
                acc = dot2acc(u.h[0], w[4 * q],     acc);
                acc = dot2acc(u.h[1], w[4 * q + 1], acc);
                acc = dot2acc(u.h[2], w[4 * q + 2], acc);
                acc = dot2acc(u.h[3], w[4 * q + 3], acc);
            }
            float y = (acc + bia) * sc + sh;   // BN
            y = fmaxf(y, 0.f);                 // relu(elu(x)) == relu(x)
            // write at OUTPUT layout index (b, roi=i, t, hb, f2)
            hbuf[((((long)bb * ROI + i) * T_ + t) * H_ + hb) * 96 + f2] = y;
        }
    }
}

// ---------------------------------------------------------------------------
// Stage C: GRU, one WG per (roi, half-of-12-sequences). Weight rows live in
// VGPRs (f16x2); xp projection fused (reads h from d_out, overwrites in place).
// ---------------------------------------------------------------------------
__global__ __launch_bounds__(576) void stageC(
    const float* __restrict__ Wih, const float* __restrict__ Whh,
    const float* __restrict__ bih, const float* __restrict__ bhh,
    float* __restrict__ io)
{
    __shared__ __align__(16) f16x2 xin[6][48];    // h_in[t] f16
    __shared__ __align__(16) f16x2 hcur[6][48];   // recurrent h f16
    __shared__ float hprev[6][96];                // recurrent h fp32 (exact state)
    __shared__ float gpre[2][6][G3];              // gate preactivations (x-side, h-side)

    const int r   = blockIdx.x >> 1;
    const int n0  = (blockIdx.x & 1) * 6;
    const int tid = threadIdx.x;
    const int mat = tid / G3;    // 0: Wih, 1: Whh
    const int g   = tid % G3;    // gate row

    // weight row -> 48 f16x2 registers (no LDS weight traffic in the T loop)
    const float* wsrc = (mat == 0 ? Wih : Whh) + ((long)r * G3 + g) * 96;
    f16x2 w[48];
    #pragma unroll 4
    for (int q = 0; q < 24; q++) {
        const float4 v = *(const float4*)(wsrc + q * 4);
        f16x2 p0 = { (_Float16)v.x, (_Float16)v.y };
        f16x2 p1 = { (_Float16)v.z, (_Float16)v.w };
        w[q * 2]     = p0;
        w[q * 2 + 1] = p1;
    }
    const float bval = (mat == 0 ? bih : bhh)[(long)r * G3 + g];

    const int n  = tid / 96;     // 0..5 (sequence within WG)
    const int k  = tid % 96;     // hidden index
    const int nn = n0 + n;       // global sequence = b*H + hb
    const int bb = nn / H_, hb = nn % H_;
    float* ioptr = io + ((((long)bb * ROI + r) * T_) * H_ + hb) * 96 + k;

    ((_Float16*)hcur)[n * 96 + k] = (_Float16)0.f;
    hprev[n][k] = 0.f;
    __syncthreads();

    for (int t = 0; t < T_; t++) {
        // stage h_in[t] (read BEFORE this step's output overwrites it)
        const float xv = ioptr[t * (H_ * 96)];
        ((_Float16*)xin)[n * 96 + k] = (_Float16)xv;
        __syncthreads();

        // gate preactivations: thread (mat,g) computes acc for all 6 sequences
        const F4H* src = (const F4H*)(mat == 0 ? &xin[0][0] : &hcur[0][0]);
        #pragma unroll
        for (int nq = 0; nq < 6; nq++) {
            float acc = bval;
            #pragma unroll
            for (int q = 0; q < 12; q++) {
                F4H u = src[nq * 12 + q];
                acc = dot2acc(u.h[0], w[4 * q],     acc);
                acc = dot2acc(u.h[1], w[4 * q + 1], acc);
                acc = dot2acc(u.h[2], w[4 * q + 2], acc);
                acc = dot2acc(u.h[3], w[4 * q + 3], acc);
            }
            gpre[mat][nq][g] = acc;
        }
        __syncthreads();

        // GRU elementwise update: 576 threads == exactly 6 n x 96 k
        const float xr = gpre[0][n][k],        hr = gpre[1][n][k];
        const float xz = gpre[0][n][96 + k],   hz = gpre[1][n][96 + k];
        const float xn = gpre[0][n][192 + k],  hn = gpre[1][n][192 + k];
        const float rg = 1.f / (1.f + __expf(-(xr + hr)));
        const float zg = 1.f / (1.f + __expf(-(xz + hz)));
        const float pre = xn + rg * hn;
        const float ng = 1.f - 2.f / (__expf(2.f * pre) + 1.f);  // tanh
        const float hnew = (1.f - zg) * ng + zg * hprev[n][k];
        hprev[n][k] = hnew;
        ((_Float16*)hcur)[n * 96 + k] = (_Float16)hnew;
        ioptr[t * (H_ * 96)] = hnew;   // overwrite h_in[t] with output[t]
        __syncthreads();
    }
}

extern "C" void kernel_launch(void* const* d_in, const int* in_sizes, int n_in,
                              void* d_out, int out_size, void* d_ws, size_t ws_size,
                              hipStream_t stream) {
    (void)in_sizes; (void)n_in; (void)out_size; (void)d_ws; (void)ws_size;
    const float* x   = (const float*)d_in[0];
    const float* a   = (const float*)d_in[1];
    const float* eps = (const float*)d_in[2];
    const float* W1  = (const float*)d_in[3];
    const float* b1  = (const float*)d_in[4];
    const float* g1  = (const float*)d_in[5];
    const float* be1 = (const float*)d_in[6];
    const float* W2  = (const float*)d_in[7];
    const float* b2  = (const float*)d_in[8];
    const float* g2  = (const float*)d_in[9];
    const float* be2 = (const float*)d_in[10];
    const float* Wih = (const float*)d_in[11];
    const float* Whh = (const float*)d_in[12];
    const float* bih = (const float*)d_in[13];
    const float* bhh = (const float*)d_in[14];
    float* out = (float*)d_out;

    stageA<<<B_ * T_ * H_, 384, 0, stream>>>(x, a, eps, W1, b1, g1, be1,
                                             W2, b2, g2, be2, out);
    stageC<<<ROI * 2, 576, 0, stream>>>(Wih, Whh, bih, bhh, out);
}

// Round 2
// 2170.815 us; speedup vs baseline: 2.4650x; 2.4650x over previous
//
#include <hip/hip_runtime.h>

#define B_  4
#define ROI 90
#define T_  200
#define H_  3
#define F_  96
#define G3  288
#define NSEQ 4           // sequences per stageC workgroup (12 = 3 WGs x 4)

typedef _Float16 f16x2 __attribute__((ext_vector_type(2)));
typedef _Float16 f16x8 __attribute__((ext_vector_type(8)));

__device__ __forceinline__ float dot2acc(f16x2 a, f16x2 b, float c) {
#if __has_builtin(__builtin_amdgcn_fdot2)
    return __builtin_amdgcn_fdot2(a, b, c, false);
#else
    return c + (float)a.x * (float)b.x + (float)a.y * (float)b.y;
#endif
}

// 8-term dot: u (f16x8, one ds_read_b128) vs 4 f16x2 weight regs.
// f16x2 slices of f16x8 are adjacent VGPR halves -> extraction is free.
__device__ __forceinline__ float dot8(f16x8 u, f16x2 w0, f16x2 w1, f16x2 w2,
                                      f16x2 w3, float acc) {
    f16x2 p0 = { u[0], u[1] }, p1 = { u[2], u[3] };
    f16x2 p2 = { u[4], u[5] }, p3 = { u[6], u[7] };
    acc = dot2acc(p0, w0, acc);
    acc = dot2acc(p1, w1, acc);
    acc = dot2acc(p2, w2, acc);
    acc = dot2acc(p3, w3, acc);
    return acc;
}

// ---------------------------------------------------------------------------
// Stage A: per-(b,t,h) block: sparse aggregation + 2-layer MLP (BN+ELU) + relu
// Writes h into d_out at the FINAL output layout index (b, roi, t, hb, f) so
// stage C can run the GRU in place (read-before-overwrite per t).
// ---------------------------------------------------------------------------
__global__ __launch_bounds__(384) void stageA(
    const float* __restrict__ x, const float* __restrict__ a,
    const float* __restrict__ eps,
    const float* __restrict__ W1, const float* __restrict__ b1,
    const float* __restrict__ g1, const float* __restrict__ be1,
    const float* __restrict__ W2, const float* __restrict__ b2,
    const float* __restrict__ g2, const float* __restrict__ be2,
    float* __restrict__ hbuf)
{
    __shared__ __align__(16) f16x2 xs[ROI][48];   // x tile f16; reused as h1
    __shared__ __align__(16) f16x2 agg[ROI][48];  // aggregated tile f16
    __shared__ __align__(16) f16x2 wbuf[96][49];  // W1 then W2 (transposed, padded)
    __shared__ unsigned char jl[ROI][ROI];        // per-row nonzero col indices
    __shared__ int cnt[ROI];

    const int blk = blockIdx.x;
    const int bb  = blk / (T_ * H_);
    const int rem = blk % (T_ * H_);
    const int t   = rem / H_;
    const int hb  = rem % H_;
    const int tid = threadIdx.x;

    // ---- load x tile (90 x 96 fp32 -> f16 pairs) ----
    for (int idx = tid; idx < ROI * 24; idx += 384) {
        const int j = idx / 24, c4 = idx % 24;
        const float4 v = *(const float4*)(x + ((((long)bb * ROI + j) * T_ + t) * H_ + hb) * F_ + c4 * 4);
        f16x2 p0 = { (_Float16)v.x, (_Float16)v.y };
        f16x2 p1 = { (_Float16)v.z, (_Float16)v.w };
        xs[j][c4 * 2]     = p0;
        xs[j][c4 * 2 + 1] = p1;
    }
    // ---- load W1 transposed+paired ----
    for (int idx = tid; idx < 48 * 96; idx += 384) {
        const int f2 = idx % 96, fp = idx / 96;
        f16x2 p = { (_Float16)W1[(2 * fp) * 96 + f2], (_Float16)W1[(2 * fp + 1) * 96 + f2] };
        wbuf[f2][fp] = p;
    }
    if (tid < ROI) cnt[tid] = 0;
    const float epsv = eps[0];
    __syncthreads();

    // ---- compress adjacency (mask = a != 0 -> exact 1.0 weights -> adds) ----
    for (int idx = tid; idx < ROI * ROI; idx += 384) {
        const int i = idx / ROI, j = idx % ROI;
        const float av = a[((((long)bb * ROI + i) * T_ + t) * H_ + hb) * ROI + j];
        if (av != 0.0f) {
            const int p = atomicAdd(&cnt[i], 1);
            jl[i][p] = (unsigned char)j;
        }
    }
    __syncthreads();

    // ---- agg[i] = sum_{j in list(i)} xs[j] + eps * xs[i] ----
    for (int idx = tid; idx < ROI * 48; idx += 384) {
        const int i = idx / 48, p = idx % 48;
        float s0 = 0.f, s1 = 0.f;
        const int c = cnt[i];
        for (int q = 0; q < c; q++) {
            const f16x2 v = xs[jl[i][q]][p];
            s0 += (float)v.x; s1 += (float)v.y;
        }
        const f16x2 xi = xs[i][p];
        s0 += epsv * (float)xi.x;
        s1 += epsv * (float)xi.y;
        f16x2 o = { (_Float16)s0, (_Float16)s1 };
        agg[i][p] = o;
    }
    __syncthreads();

    const int f2 = tid % 96, isub = tid / 96;   // thread owns output column f2
    f16x2 w[48];
    #pragma unroll
    for (int p = 0; p < 48; p++) w[p] = wbuf[f2][p];
    {
        const float bia = b1[f2];
        const float sc  = g1[f2] * rsqrtf(1.0f + 1e-5f);
        const float sh  = be1[f2];
        _Float16* h1h = (_Float16*)xs;   // xs no longer needed; reuse for h1
        for (int i = isub; i < ROI; i += 4) {
            const f16x8* ar = (const f16x8*)&agg[i][0];
            float acc = 0.f;
            #pragma unroll
            for (int q = 0; q < 12; q++) {
                f16x8 u = ar[q];
                acc = dot8(u, w[4*q], w[4*q+1], w[4*q+2], w[4*q+3], acc);
            }
            float y = (acc + bia) * sc + sh;   // BN (eval mode)
            y = y > 0.f ? y : expm1f(y);       // ELU
            h1h[i * 96 + f2] = (_Float16)y;
        }
    }
    __syncthreads();
    // ---- reload W2 over the same buffer (keeps LDS <= 62 KB) ----
    for (int idx = tid; idx < 48 * 96; idx += 384) {
        const int f2b = idx % 96, fp = idx / 96;
        f16x2 p = { (_Float16)W2[(2 * fp) * 96 + f2b], (_Float16)W2[(2 * fp + 1) * 96 + f2b] };
        wbuf[f2b][fp] = p;
    }
    __syncthreads();
    #pragma unroll
    for (int p = 0; p < 48; p++) w[p] = wbuf[f2][p];
    {
        const float bia = b2[f2];
        const float sc  = g2[f2] * rsqrtf(1.0f + 1e-5f);
        const float sh  = be2[f2];
        for (int i = isub; i < ROI; i += 4) {
            const f16x8* hr = (const f16x8*)&xs[i][0];
            float acc = 0.f;
            #pragma unroll
            for (int q = 0; q < 12; q++) {
                f16x8 u = hr[q];
                acc = dot8(u, w[4*q], w[4*q+1], w[4*q+2], w[4*q+3], acc);
            }
            float y = (acc + bia) * sc + sh;   // BN
            y = fmaxf(y, 0.f);                 // relu(elu(x)) == relu(x)
            hbuf[((((long)bb * ROI + i) * T_ + t) * H_ + hb) * 96 + f2] = y;
        }
    }
}

// ---------------------------------------------------------------------------
// Stage C: GRU. One WG per (roi, third-of-12-sequences): 270 WGs, 576 thr.
// Weight rows (96 f16) live in VGPRs; per-step LDS reads have 4-way ILP;
// next timestep's input is prefetched across the dot phase.
// ---------------------------------------------------------------------------
__global__ __launch_bounds__(576) void stageC(
    const float* __restrict__ Wih, const float* __restrict__ Whh,
    const float* __restrict__ bih, const float* __restrict__ bhh,
    float* __restrict__ io)
{
    __shared__ __align__(16) f16x8 xin[NSEQ][12];    // h_in[t] f16
    __shared__ __align__(16) f16x8 hcur[NSEQ][12];   // recurrent h f16
    __shared__ float hprev[NSEQ][96];                // recurrent h fp32 (exact)
    __shared__ float gpre[2][NSEQ][G3];              // gate preactivations

    const int r   = blockIdx.x / 3;
    const int n0  = (blockIdx.x % 3) * NSEQ;
    const int tid = threadIdx.x;
    const int mat = tid / G3;    // 0: Wih, 1: Whh
    const int g   = tid % G3;    // gate row

    // weight row -> 48 f16x2 registers
    const float* wsrc = (mat == 0 ? Wih : Whh) + ((long)r * G3 + g) * 96;
    f16x2 w[48];
    #pragma unroll 4
    for (int q = 0; q < 24; q++) {
        const float4 v = *(const float4*)(wsrc + q * 4);
        f16x2 p0 = { (_Float16)v.x, (_Float16)v.y };
        f16x2 p1 = { (_Float16)v.z, (_Float16)v.w };
        w[q * 2]     = p0;
        w[q * 2 + 1] = p1;
    }
    const float bval = (mat == 0 ? bih : bhh)[(long)r * G3 + g];

    const int n  = tid / 96;     // sequence within WG (valid if < NSEQ)
    const int k  = tid % 96;     // hidden index
    const int nn = n0 + (n < NSEQ ? n : 0);
    const int bb = nn / H_, hb = nn % H_;
    float* ioptr = io + ((((long)bb * ROI + r) * T_) * H_ + hb) * 96 + k;
    const bool owns = (n < NSEQ);

    if (owns) {
        ((_Float16*)hcur)[n * 96 + k] = (_Float16)0.f;
        hprev[n][k] = 0.f;
    }
    float xv = owns ? ioptr[0] : 0.f;
    __syncthreads();

    for (int t = 0; t < T_; t++) {
        if (owns) ((_Float16*)xin)[n * 96 + k] = (_Float16)xv;
        __syncthreads();                       // B1: xin + hcur ready

        // prefetch next timestep's input; drained at B2 (overlaps dot phase)
        float xnext = 0.f;
        if (owns && t + 1 < T_) xnext = ioptr[(t + 1) * (H_ * 96)];

        // gate preactivations: thread (mat,g) for all NSEQ sequences;
        // per-q reads across sequences are independent -> 4-way load ILP
        const f16x8* src = (mat == 0) ? &xin[0][0] : &hcur[0][0];
        float acc[NSEQ];
        #pragma unroll
        for (int nq = 0; nq < NSEQ; nq++) acc[nq] = bval;
        #pragma unroll
        for (int q = 0; q < 12; q++) {
            f16x8 u0 = src[0 * 12 + q];
            f16x8 u1 = src[1 * 12 + q];
            f16x8 u2 = src[2 * 12 + q];
            f16x8 u3 = src[3 * 12 + q];
            acc[0] = dot8(u0, w[4*q], w[4*q+1], w[4*q+2], w[4*q+3], acc[0]);
            acc[1] = dot8(u1, w[4*q], w[4*q+1], w[4*q+2], w[4*q+3], acc[1]);
            acc[2] = dot8(u2, w[4*q], w[4*q+1], w[4*q+2], w[4*q+3], acc[2]);
            acc[3] = dot8(u3, w[4*q], w[4*q+1], w[4*q+2], w[4*q+3], acc[3]);
        }
        #pragma unroll
        for (int nq = 0; nq < NSEQ; nq++) gpre[mat][nq][g] = acc[nq];
        __syncthreads();                       // B2: gpre ready

        if (owns) {
            const float xr = gpre[0][n][k],       hr = gpre[1][n][k];
            const float xz = gpre[0][n][96 + k],  hz = gpre[1][n][96 + k];
            const float xn = gpre[0][n][192 + k], hn = gpre[1][n][192 + k];
            const float rg = 1.f / (1.f + __expf(-(xr + hr)));
            const float zg = 1.f / (1.f + __expf(-(xz + hz)));
            const float pre = xn + rg * hn;
            const float ng = 1.f - 2.f / (__expf(2.f * pre) + 1.f);  // tanh
            const float hnew = (1.f - zg) * ng + zg * hprev[n][k];
            hprev[n][k] = hnew;
            ((_Float16*)hcur)[n * 96 + k] = (_Float16)hnew;
            ioptr[t * (H_ * 96)] = hnew;       // overwrite h_in[t] with out[t]
        }
        __syncthreads();                       // B3: hcur/xin safe to rewrite
        xv = xnext;
    }
}

extern "C" void kernel_launch(void* const* d_in, const int* in_sizes, int n_in,
                              void* d_out, int out_size, void* d_ws, size_t ws_size,
                              hipStream_t stream) {
    (void)in_sizes; (void)n_in; (void)out_size; (void)d_ws; (void)ws_size;
    const float* x   = (const float*)d_in[0];
    const float* a   = (const float*)d_in[1];
    const float* eps = (const float*)d_in[2];
    const float* W1  = (const float*)d_in[3];
    const float* b1  = (const float*)d_in[4];
    const float* g1  = (const float*)d_in[5];
    const float* be1 = (const float*)d_in[6];
    const float* W2  = (const float*)d_in[7];
    const float* b2  = (const float*)d_in[8];
    const float* g2  = (const float*)d_in[9];
    const float* be2 = (const float*)d_in[10];
    const float* Wih = (const float*)d_in[11];
    const float* Whh = (const float*)d_in[12];
    const float* bih = (const float*)d_in[13];
    const float* bhh = (const float*)d_in[14];
    float* out = (float*)d_out;

    stageA<<<B_ * T_ * H_, 384, 0, stream>>>(x, a, eps, W1, b1, g1, be1,
                                             W2, b2, g2, be2, out);
    stageC<<<ROI * 3, 576, 0, stream>>>(Wih, Whh, bih, bhh, out);
}

// Round 3
// 2042.416 us; speedup vs baseline: 2.6199x; 1.0629x over previous
//
#include <hip/hip_runtime.h>

#define B_  4
#define ROI 90
#define T_  200
#define H_  3
#define F_  96
#define G3  288
#define NSEQ 4           // sequences per stageC workgroup (12 = 3 WGs x 4)
#define TB  8            // timestep batching for global I/O

typedef _Float16 f16x2 __attribute__((ext_vector_type(2)));
typedef _Float16 f16x8 __attribute__((ext_vector_type(8)));

__device__ __forceinline__ float dot2acc(f16x2 a, f16x2 b, float c) {
#if __has_builtin(__builtin_amdgcn_fdot2)
    return __builtin_amdgcn_fdot2(a, b, c, false);
#else
    return c + (float)a.x * (float)b.x + (float)a.y * (float)b.y;
#endif
}

// 8-term dot: u (f16x8, one ds_read_b128) vs 4 f16x2 weight regs.
__device__ __forceinline__ float dot8(f16x8 u, f16x2 w0, f16x2 w1, f16x2 w2,
                                      f16x2 w3, float acc) {
    f16x2 p0 = { u[0], u[1] }, p1 = { u[2], u[3] };
    f16x2 p2 = { u[4], u[5] }, p3 = { u[6], u[7] };
    acc = dot2acc(p0, w0, acc);
    acc = dot2acc(p1, w1, acc);
    acc = dot2acc(p2, w2, acc);
    acc = dot2acc(p3, w3, acc);
    return acc;
}

// ---------------------------------------------------------------------------
// Stage A: per-(b,t,h) block: sparse aggregation + 2-layer MLP (BN+ELU) + relu
// Writes h into d_out at the FINAL output layout index (b, roi, t, hb, f) so
// stage C can run the GRU in place (read-before-overwrite per t).
// launch_bounds(384,2): VGPR cap 256 so the 48-reg weight column stays
// resident (default heuristic capped VGPRs and spilled it to scratch).
// ---------------------------------------------------------------------------
__global__ __launch_bounds__(384, 2) void stageA(
    const float* __restrict__ x, const float* __restrict__ a,
    const float* __restrict__ eps,
    const float* __restrict__ W1, const float* __restrict__ b1,
    const float* __restrict__ g1, const float* __restrict__ be1,
    const float* __restrict__ W2, const float* __restrict__ b2,
    const float* __restrict__ g2, const float* __restrict__ be2,
    float* __restrict__ hbuf)
{
    __shared__ __align__(16) f16x2 xs[ROI][48];   // x tile f16; reused as h1
    __shared__ __align__(16) f16x2 agg[ROI][48];  // aggregated tile f16
    __shared__ __align__(16) f16x2 wbuf[96][49];  // W1 then W2 (transposed, padded)
    __shared__ unsigned char jl[ROI][ROI];        // per-row nonzero col indices
    __shared__ int cnt[ROI];

    const int blk = blockIdx.x;
    const int bb  = blk / (T_ * H_);
    const int rem = blk % (T_ * H_);
    const int t   = rem / H_;
    const int hb  = rem % H_;
    const int tid = threadIdx.x;

    // ---- load x tile (90 x 96 fp32 -> f16 pairs) ----
    for (int idx = tid; idx < ROI * 24; idx += 384) {
        const int j = idx / 24, c4 = idx % 24;
        const float4 v = *(const float4*)(x + ((((long)bb * ROI + j) * T_ + t) * H_ + hb) * F_ + c4 * 4);
        f16x2 p0 = { (_Float16)v.x, (_Float16)v.y };
        f16x2 p1 = { (_Float16)v.z, (_Float16)v.w };
        xs[j][c4 * 2]     = p0;
        xs[j][c4 * 2 + 1] = p1;
    }
    // ---- load W1 transposed+paired ----
    for (int idx = tid; idx < 48 * 96; idx += 384) {
        const int f2 = idx % 96, fp = idx / 96;
        f16x2 p = { (_Float16)W1[(2 * fp) * 96 + f2], (_Float16)W1[(2 * fp + 1) * 96 + f2] };
        wbuf[f2][fp] = p;
    }
    if (tid < ROI) cnt[tid] = 0;
    const float epsv = eps[0];
    __syncthreads();

    // ---- compress adjacency (mask = a != 0 -> exact 1.0 weights -> adds) ----
    for (int idx = tid; idx < ROI * ROI; idx += 384) {
        const int i = idx / ROI, j = idx % ROI;
        const float av = a[((((long)bb * ROI + i) * T_ + t) * H_ + hb) * ROI + j];
        if (av != 0.0f) {
            const int p = atomicAdd(&cnt[i], 1);
            jl[i][p] = (unsigned char)j;
        }
    }
    __syncthreads();

    // ---- agg[i] = sum_{j in list(i)} xs[j] + eps * xs[i] ----
    for (int idx = tid; idx < ROI * 48; idx += 384) {
        const int i = idx / 48, p = idx % 48;
        float s0 = 0.f, s1 = 0.f;
        const int c = cnt[i];
        for (int q = 0; q < c; q++) {
            const f16x2 v = xs[jl[i][q]][p];
            s0 += (float)v.x; s1 += (float)v.y;
        }
        const f16x2 xi = xs[i][p];
        s0 += epsv * (float)xi.x;
        s1 += epsv * (float)xi.y;
        f16x2 o = { (_Float16)s0, (_Float16)s1 };
        agg[i][p] = o;
    }
    __syncthreads();

    const int f2 = tid % 96, isub = tid / 96;   // thread owns output column f2
    f16x2 w[48];
    #pragma unroll
    for (int p = 0; p < 48; p++) w[p] = wbuf[f2][p];
    {
        const float bia = b1[f2];
        const float sc  = g1[f2] * rsqrtf(1.0f + 1e-5f);
        const float sh  = be1[f2];
        _Float16* h1h = (_Float16*)xs;   // xs no longer needed; reuse for h1
        for (int i = isub; i < ROI; i += 4) {
            const f16x8* ar = (const f16x8*)&agg[i][0];
            float acc = 0.f;
            #pragma unroll
            for (int q = 0; q < 12; q++) {
                f16x8 u = ar[q];
                acc = dot8(u, w[4*q], w[4*q+1], w[4*q+2], w[4*q+3], acc);
            }
            float y = (acc + bia) * sc + sh;   // BN (eval mode)
            y = y > 0.f ? y : expm1f(y);       // ELU
            h1h[i * 96 + f2] = (_Float16)y;
        }
    }
    __syncthreads();
    // ---- reload W2 over the same buffer (keeps LDS <= 62 KB) ----
    for (int idx = tid; idx < 48 * 96; idx += 384) {
        const int f2b = idx % 96, fp = idx / 96;
        f16x2 p = { (_Float16)W2[(2 * fp) * 96 + f2b], (_Float16)W2[(2 * fp + 1) * 96 + f2b] };
        wbuf[f2b][fp] = p;
    }
    __syncthreads();
    #pragma unroll
    for (int p = 0; p < 48; p++) w[p] = wbuf[f2][p];
    {
        const float bia = b2[f2];
        const float sc  = g2[f2] * rsqrtf(1.0f + 1e-5f);
        const float sh  = be2[f2];
        for (int i = isub; i < ROI; i += 4) {
            const f16x8* hr = (const f16x8*)&xs[i][0];
            float acc = 0.f;
            #pragma unroll
            for (int q = 0; q < 12; q++) {
                f16x8 u = hr[q];
                acc = dot8(u, w[4*q], w[4*q+1], w[4*q+2], w[4*q+3], acc);
            }
            float y = (acc + bia) * sc + sh;   // BN
            y = fmaxf(y, 0.f);                 // relu(elu(x)) == relu(x)
            hbuf[((((long)bb * ROI + i) * T_ + t) * H_ + hb) * 96 + f2] = y;
        }
    }
}

// ---------------------------------------------------------------------------
// Stage C: GRU. One WG per (roi, third-of-12-sequences): 270 WGs, 576 thr.
// Weight rows in VGPRs (launch_bounds(576,2) prevents the scratch spill that
// dominated rounds 1-2). 2 barriers/step; global I/O batched TB=8 steps so
// most barriers' implicit vmcnt(0) has nothing to drain.
// ---------------------------------------------------------------------------
__global__ __launch_bounds__(576, 2) void stageC(
    const float* __restrict__ Wih, const float* __restrict__ Whh,
    const float* __restrict__ bih, const float* __restrict__ bhh,
    float* __restrict__ io)
{
    __shared__ __align__(16) f16x8 xin[NSEQ][12];    // h_in[t] f16
    __shared__ __align__(16) f16x8 hcur[NSEQ][12];   // recurrent h f16
    __shared__ float hprev[NSEQ][96];                // recurrent h fp32 (exact)
    __shared__ float gpre[2][NSEQ][G3];              // gate preactivations

    const int r   = blockIdx.x / 3;
    const int n0  = (blockIdx.x % 3) * NSEQ;
    const int tid = threadIdx.x;
    const int mat = tid / G3;    // 0: Wih, 1: Whh
    const int g   = tid % G3;    // gate row

    // weight row -> 48 f16x2 registers
    const float* wsrc = (mat == 0 ? Wih : Whh) + ((long)r * G3 + g) * 96;
    f16x2 w[48];
    #pragma unroll 4
    for (int q = 0; q < 24; q++) {
        const float4 v = *(const float4*)(wsrc + q * 4);
        f16x2 p0 = { (_Float16)v.x, (_Float16)v.y };
        f16x2 p1 = { (_Float16)v.z, (_Float16)v.w };
        w[q * 2]     = p0;
        w[q * 2 + 1] = p1;
    }
    const float bval = (mat == 0 ? bih : bhh)[(long)r * G3 + g];

    const int n  = tid / 96;     // sequence within WG (valid if < NSEQ)
    const int k  = tid % 96;     // hidden index
    const int nn = n0 + (n < NSEQ ? n : 0);
    const int bb = nn / H_, hb = nn % H_;
    float* ioptr = io + ((((long)bb * ROI + r) * T_) * H_ + hb) * 96 + k;
    const bool owns = (n < NSEQ);

    // initial input batch t = 0..TB-1
    float cur[TB];
    #pragma unroll
    for (int j = 0; j < TB; j++) cur[j] = owns ? ioptr[j * (H_ * 96)] : 0.f;

    if (owns) {
        ((_Float16*)hcur)[n * 96 + k] = (_Float16)0.f;
        hprev[n][k] = 0.f;
        ((_Float16*)xin)[n * 96 + k] = (_Float16)cur[0];
    }
    __syncthreads();   // B0: xin/hcur ready for t=0

    for (int tt = 0; tt < T_ / TB; tt++) {
        float nxt[TB], out8[TB];
        #pragma unroll
        for (int j = 0; j < TB; j++) nxt[j] = 0.f;

        for (int j = 0; j < TB; j++) {
            // prefetch next superstep's inputs once; drains at this step's B2
            if (j == 0 && owns && tt + 1 < T_ / TB) {
                #pragma unroll
                for (int p = 0; p < TB; p++)
                    nxt[p] = ioptr[((tt + 1) * TB + p) * (H_ * 96)];
            }

            // gate preactivations: thread (mat,g) for all NSEQ sequences
            const f16x8* src = (mat == 0) ? &xin[0][0] : &hcur[0][0];
            float acc[NSEQ];
            #pragma unroll
            for (int nq = 0; nq < NSEQ; nq++) acc[nq] = bval;
            #pragma unroll
            for (int q = 0; q < 12; q++) {
                f16x8 u0 = src[0 * 12 + q];
                f16x8 u1 = src[1 * 12 + q];
                f16x8 u2 = src[2 * 12 + q];
                f16x8 u3 = src[3 * 12 + q];
                acc[0] = dot8(u0, w[4*q], w[4*q+1], w[4*q+2], w[4*q+3], acc[0]);
                acc[1] = dot8(u1, w[4*q], w[4*q+1], w[4*q+2], w[4*q+3], acc[1]);
                acc[2] = dot8(u2, w[4*q], w[4*q+1], w[4*q+2], w[4*q+3], acc[2]);
                acc[3] = dot8(u3, w[4*q], w[4*q+1], w[4*q+2], w[4*q+3], acc[3]);
            }
            #pragma unroll
            for (int nq = 0; nq < NSEQ; nq++) gpre[mat][nq][g] = acc[nq];
            __syncthreads();                       // B2: gpre ready

            if (owns) {
                const float xr = gpre[0][n][k],       hr = gpre[1][n][k];
                const float xz = gpre[0][n][96 + k],  hz = gpre[1][n][96 + k];
                const float xn = gpre[0][n][192 + k], hn = gpre[1][n][192 + k];
                const float rg = 1.f / (1.f + __expf(-(xr + hr)));
                const float zg = 1.f / (1.f + __expf(-(xz + hz)));
                const float pre = xn + rg * hn;
                const float ng = 1.f - 2.f / (__expf(2.f * pre) + 1.f);  // tanh
                const float hnew = (1.f - zg) * ng + zg * hprev[n][k];
                hprev[n][k] = hnew;
                out8[j] = hnew;
                ((_Float16*)hcur)[n * 96 + k] = (_Float16)hnew;
                // stage NEXT step's input now (input regs already resident)
                ((_Float16*)xin)[n * 96 + k] =
                    (_Float16)(j + 1 < TB ? cur[j + 1] : nxt[0]);
            }
            __syncthreads();                       // B3: xin/hcur ready for t+1
        }

        // batched output write; drains at next superstep's first B2
        if (owns) {
            #pragma unroll
            for (int j = 0; j < TB; j++)
                ioptr[(tt * TB + j) * (H_ * 96)] = out8[j];
        }
        #pragma unroll
        for (int j = 0; j < TB; j++) cur[j] = nxt[j];
    }
}

extern "C" void kernel_launch(void* const* d_in, const int* in_sizes, int n_in,
                              void* d_out, int out_size, void* d_ws, size_t ws_size,
                              hipStream_t stream) {
    (void)in_sizes; (void)n_in; (void)out_size; (void)d_ws; (void)ws_size;
    const float* x   = (const float*)d_in[0];
    const float* a   = (const float*)d_in[1];
    const float* eps = (const float*)d_in[2];
    const float* W1  = (const float*)d_in[3];
    const float* b1  = (const float*)d_in[4];
    const float* g1  = (const float*)d_in[5];
    const float* be1 = (const float*)d_in[6];
    const float* W2  = (const float*)d_in[7];
    const float* b2  = (const float*)d_in[8];
    const float* g2  = (const float*)d_in[9];
    const float* be2 = (const float*)d_in[10];
    const float* Wih = (const float*)d_in[11];
    const float* Whh = (const float*)d_in[12];
    const float* bih = (const float*)d_in[13];
    const float* bhh = (const float*)d_in[14];
    float* out = (float*)d_out;

    stageA<<<B_ * T_ * H_, 384, 0, stream>>>(x, a, eps, W1, b1, g1, be1,
                                             W2, b2, g2, be2, out);
    stageC<<<ROI * 3, 576, 0, stream>>>(Wih, Whh, bih, bhh, out);
}